// Round 5
// baseline (568.364 us; speedup 1.0000x reference)
//
#include <hip/hip_runtime.h>

// Sparsemax rows: x [16384,4096] fp32 -> out. WAVE-PER-ROW, ZERO barriers,
// ZERO LDS. Every __syncthreads lowers to s_waitcnt vmcnt(0)+s_barrier on
// gfx950, draining the load queue each row (R1-R4 plateau ~143us vs 63us HBM
// floor). Here waves are fully autonomous: shuffle reductions only, loads
// stream with no drains. Row data is NOT kept in registers: 3 cheap re-read
// passes (R2/R3 proved re-reads are L1/L2/L3-absorbed: FETCH unchanged).
// tau: support subset of {x > rowmax-1} (~14/row); candidates into 4 reg
// slots/lane; Michelot fixed point via shuffles. Overflow (>4 cand in one
// lane, ~1e-4 of rows) -> binary-search fallback on cache-hot re-reads.

constexpr int COLS = 4096;
constexpr int TPB  = 256;     // 4 independent waves per block
constexpr int WPB  = 4;

using f32x4 = __attribute__((ext_vector_type(4))) float;

__device__ __forceinline__ float wred_sum(float v) {
    #pragma unroll
    for (int m = 32; m; m >>= 1) v += __shfl_xor(v, m, 64);
    return v;
}
__device__ __forceinline__ float wred_max(float v) {
    #pragma unroll
    for (int m = 32; m; m >>= 1) v = fmaxf(v, __shfl_xor(v, m, 64));
    return v;
}
// Launder a row pointer through an opaque 0 offset so the compiler cannot
// CSE loads between passes (which would force 64 live VGPRs per lane).
__device__ __forceinline__ const f32x4* launder(const float* p) {
    unsigned long long z = 0;
    asm volatile("" : "+s"(z));
    return reinterpret_cast<const f32x4*>(reinterpret_cast<const char*>(p) + z);
}

__global__ __launch_bounds__(TPB, 8) void sparsemax_kernel(const float* __restrict__ x,
                                                           float* __restrict__ out) {
    const int lane = threadIdx.x & 63;
    const int row  = blockIdx.x * WPB + (threadIdx.x >> 6);
    const float* rowp = x + (size_t)row * COLS;
    float*       outp = out + (size_t)row * COLS;

    // ---- pass 1: row max (values discarded -> low VGPR, pure stream) ----
    const f32x4* xr1 = reinterpret_cast<const f32x4*>(rowp);
    float mx = -3.4e38f;
    #pragma unroll
    for (int j = 0; j < 16; ++j) {
        f32x4 q = xr1[lane + 64 * j];
        mx = fmaxf(mx, fmaxf(fmaxf(q.x, q.y), fmaxf(q.z, q.w)));
    }
    mx = wred_max(mx);
    const float lb = mx - 1.0f;    // tau* >= rowmax-1 -> support subset of {x > lb}

    // ---- pass 2: extract candidates {x > lb} into 4 reg slots/lane ----
    const f32x4* xr2 = launder(rowp);
    float c0 = -3.4e38f, c1 = -3.4e38f, c2 = -3.4e38f, c3 = -3.4e38f;
    int k = 0;
    #pragma unroll
    for (int j = 0; j < 16; ++j) {
        f32x4 q = xr2[lane + 64 * j];
        float e[4] = {q.x, q.y, q.z, q.w};
        #pragma unroll
        for (int t = 0; t < 4; ++t) {
            float xv = e[t];
            if (xv > lb) {
                if      (k == 0) c0 = xv;
                else if (k == 1) c1 = xv;
                else if (k == 2) c2 = xv;
                else if (k == 3) c3 = xv;
                ++k;
            }
        }
    }
    const bool ovf = (__ballot(k > 4) != 0ULL);   // wave-uniform

    float tau;
    if (!ovf) {
        // ---- Michelot fixed point on register slots, shuffles only ----
        // invalid slots are -3.4e38 < lb <= t, never pass the filter.
        float s   = ((c0 > lb) ? c0 : 0.f) + ((c1 > lb) ? c1 : 0.f)
                  + ((c2 > lb) ? c2 : 0.f) + ((c3 > lb) ? c3 : 0.f);
        float cnt = ((c0 > lb) ? 1.f : 0.f) + ((c1 > lb) ? 1.f : 0.f)
                  + ((c2 > lb) ? 1.f : 0.f) + ((c3 > lb) ? 1.f : 0.f);
        s = wred_sum(s); cnt = wred_sum(cnt);      // cnt >= 1 (rowmax in slots)
        float t = (s - 1.f) / cnt;                 // t0 <= tau*, ascends to tau*
        for (int it = 0; it < 260; ++it) {         // set shrinks each iter, <=257
            float si = ((c0 > t) ? c0 : 0.f) + ((c1 > t) ? c1 : 0.f)
                     + ((c2 > t) ? c2 : 0.f) + ((c3 > t) ? c3 : 0.f);
            float ci = ((c0 > t) ? 1.f : 0.f) + ((c1 > t) ? 1.f : 0.f)
                     + ((c2 > t) ? 1.f : 0.f) + ((c3 > t) ? 1.f : 0.f);
            si = wred_sum(si); ci = wred_sum(ci);
            float nt = (si - 1.f) / ci;
            if (nt == t) break;                    // wave-uniform exact fixpoint
            t = nt;
        }
        tau = t;
    } else {
        // ---- fallback (pathological): binary search over cache-hot re-reads ----
        float lo = lb, hi = mx;
        for (int it = 0; it < 40; ++it) {
            float mid = 0.5f * (lo + hi);
            const f32x4* xb = launder(rowp);
            float s = 0.f;
            #pragma unroll
            for (int j = 0; j < 16; ++j) {
                f32x4 q = xb[lane + 64 * j];
                s += fmaxf(q.x - mid, 0.f) + fmaxf(q.y - mid, 0.f)
                   + fmaxf(q.z - mid, 0.f) + fmaxf(q.w - mid, 0.f);
            }
            s = wred_sum(s);
            if (s > 1.f) lo = mid; else hi = mid;
        }
        const f32x4* xf = launder(rowp);
        float s = 0.f, cnt = 0.f;
        #pragma unroll
        for (int j = 0; j < 16; ++j) {
            f32x4 q = xf[lane + 64 * j];
            float e[4] = {q.x, q.y, q.z, q.w};
            #pragma unroll
            for (int t = 0; t < 4; ++t)
                if (e[t] > lo) { s += e[t]; cnt += 1.f; }
        }
        s = wred_sum(s); cnt = wred_sum(cnt);
        tau = (s - 1.f) / cnt;
    }

    // ---- pass 3: epilogue, re-read (cache-hot) + nt stores ----
    const f32x4* xr3 = launder(rowp);
    f32x4* orr = reinterpret_cast<f32x4*>(outp);
    #pragma unroll
    for (int j = 0; j < 16; ++j) {
        f32x4 q = xr3[lane + 64 * j];
        f32x4 r;
        r.x = fmaxf(q.x - tau, 0.f);
        r.y = fmaxf(q.y - tau, 0.f);
        r.z = fmaxf(q.z - tau, 0.f);
        r.w = fmaxf(q.w - tau, 0.f);
        __builtin_nontemporal_store(r, &orr[lane + 64 * j]);
    }
}

extern "C" void kernel_launch(void* const* d_in, const int* in_sizes, int n_in,
                              void* d_out, int out_size, void* d_ws, size_t ws_size,
                              hipStream_t stream) {
    const float* x = (const float*)d_in[0];
    float*       o = (float*)d_out;
    const int rows = in_sizes[0] / COLS;   // 16384
    sparsemax_kernel<<<rows / WPB, TPB, 0, stream>>>(x, o);
}

// Round 6
// 468.543 us; speedup vs baseline: 1.2130x; 1.2130x over previous
//
#include <hip/hip_runtime.h>

// Sparsemax rows: x [16384,4096] fp32 -> out. WAVE-PER-ROW, single HBM read:
// 64 floats/lane register-resident (R5 proved re-reads cost real HBM: FETCH
// 131->424 MB; R2/R3 "remat" was actually free AGPR parking). ZERO barriers,
// ZERO LDS (R3's 2 barriers + 34% occ plateaued at 165us; fills prove BW
// needs MLP not occupancy). launch_bounds(256,5): <=102 VGPR, 20 waves/CU.
// tau: support subset of {x > rowmax-1} (~14/row); candidates -> 4 reg
// slots/lane (quad-max gated, cheap common path); Michelot via shuffles
// (butterfly is bit-identical across lanes -> uniform exit). Slot overflow
// (~never for N(0,1)) -> wave-local binary search over register data.

constexpr int COLS = 4096;
constexpr int TPB  = 256;     // 4 independent waves per block
constexpr int WPB  = 4;

using f32x4 = __attribute__((ext_vector_type(4))) float;

__device__ __forceinline__ float wred_sum(float v) {
    #pragma unroll
    for (int m = 32; m; m >>= 1) v += __shfl_xor(v, m, 64);
    return v;
}
__device__ __forceinline__ float wred_max(float v) {
    #pragma unroll
    for (int m = 32; m; m >>= 1) v = fmaxf(v, __shfl_xor(v, m, 64));
    return v;
}

__global__ __launch_bounds__(TPB, 5) void sparsemax_kernel(const float* __restrict__ x,
                                                           float* __restrict__ out) {
    const int lane = threadIdx.x & 63;
    const int row  = blockIdx.x * WPB + (threadIdx.x >> 6);

    const f32x4* __restrict__ xr = reinterpret_cast<const f32x4*>(x + (size_t)row * COLS);
    f32x4* __restrict__ orr      = reinterpret_cast<f32x4*>(out + (size_t)row * COLS);

    // 16 independent coalesced 16B loads -> 64 floats/lane, pinned in regs.
    float v[64];
    #pragma unroll
    for (int j = 0; j < 16; ++j) {
        f32x4 q = xr[lane + 64 * j];
        v[4 * j + 0] = q.x; v[4 * j + 1] = q.y;
        v[4 * j + 2] = q.z; v[4 * j + 3] = q.w;
    }
    #pragma unroll
    for (int j = 0; j < 64; ++j) asm volatile("" : "+v"(v[j]));  // no remat/re-load

    // ---- quad maxes + row max (shuffle butterfly) ----
    float g[16];
    #pragma unroll
    for (int j = 0; j < 16; ++j)
        g[j] = fmaxf(fmaxf(v[4 * j], v[4 * j + 1]), fmaxf(v[4 * j + 2], v[4 * j + 3]));
    float mx = g[0];
    #pragma unroll
    for (int j = 1; j < 16; ++j) mx = fmaxf(mx, g[j]);
    mx = wred_max(mx);
    const float lb = mx - 1.0f;   // tau* >= rowmax-1 -> support subset of {x > lb}

    // ---- extract candidates {x > lb} into 4 reg slots (quad-max gated) ----
    float c0 = lb, c1 = lb, c2 = lb, c3 = lb;   // sentinel lb: never passes (>t, t>=lb)
    int k = 0;
    #pragma unroll
    for (int j = 0; j < 16; ++j) {
        if (g[j] > lb) {          // rare: ~14/4096 elements qualify per row
            #pragma unroll
            for (int e = 0; e < 4; ++e) {
                float xv = v[4 * j + e];
                if (xv > lb) {
                    if      (k == 0) c0 = xv;
                    else if (k == 1) c1 = xv;
                    else if (k == 2) c2 = xv;
                    else if (k == 3) c3 = xv;
                    ++k;
                }
            }
        }
    }

    float tau;
    if (__ballot(k > 4) == 0ULL) {
        // ---- Michelot fixed point on slots, shuffles only ----
        float s = ((c0 > lb) ? c0 : 0.f) + ((c1 > lb) ? c1 : 0.f)
                + ((c2 > lb) ? c2 : 0.f) + ((c3 > lb) ? c3 : 0.f);
        float n = ((c0 > lb) ? 1.f : 0.f) + ((c1 > lb) ? 1.f : 0.f)
                + ((c2 > lb) ? 1.f : 0.f) + ((c3 > lb) ? 1.f : 0.f);
        s = wred_sum(s); n = wred_sum(n);       // n >= 1 (rowmax is a candidate)
        float t = (s - 1.f) / n;                // t0 in [lb, tau*], ascends to tau*
        for (int it = 0; it < 260; ++it) {      // active set strictly shrinks
            float si = ((c0 > t) ? c0 : 0.f) + ((c1 > t) ? c1 : 0.f)
                     + ((c2 > t) ? c2 : 0.f) + ((c3 > t) ? c3 : 0.f);
            float ci = ((c0 > t) ? 1.f : 0.f) + ((c1 > t) ? 1.f : 0.f)
                     + ((c2 > t) ? 1.f : 0.f) + ((c3 > t) ? 1.f : 0.f);
            si = wred_sum(si); ci = wred_sum(ci);   // ci >= 1 (rowmax > tau*)
            float nt = (si - 1.f) / ci;
            if (nt == t) break;                 // bit-identical across lanes
            t = nt;
        }
        tau = t;
    } else {
        // ---- fallback (pathological): wave-local binary search over regs ----
        float lo = lb, hi = mx;
        for (int it = 0; it < 40; ++it) {
            float mid = 0.5f * (lo + hi);
            float s = 0.f;
            #pragma unroll
            for (int j = 0; j < 64; ++j) s += fmaxf(v[j] - mid, 0.f);
            s = wred_sum(s);
            if (s > 1.f) lo = mid; else hi = mid;
        }
        float s = 0.f, n = 0.f;
        #pragma unroll
        for (int j = 0; j < 64; ++j)
            if (v[j] > lo) { s += v[j]; n += 1.f; }
        s = wred_sum(s); n = wred_sum(n);
        tau = (s - 1.f) / n;
    }

    // ---- epilogue: out = max(x - tau, 0), plain coalesced dwordx4 stores ----
    #pragma unroll
    for (int j = 0; j < 16; ++j) {
        f32x4 r;
        r.x = fmaxf(v[4 * j + 0] - tau, 0.f);
        r.y = fmaxf(v[4 * j + 1] - tau, 0.f);
        r.z = fmaxf(v[4 * j + 2] - tau, 0.f);
        r.w = fmaxf(v[4 * j + 3] - tau, 0.f);
        orr[lane + 64 * j] = r;
    }
}

extern "C" void kernel_launch(void* const* d_in, const int* in_sizes, int n_in,
                              void* d_out, int out_size, void* d_ws, size_t ws_size,
                              hipStream_t stream) {
    const float* x = (const float*)d_in[0];
    float*       o = (float*)d_out;
    const int rows = in_sizes[0] / COLS;   // 16384
    sparsemax_kernel<<<rows / WPB, TPB, 0, stream>>>(x, o);
}